// Round 4
// baseline (605.347 us; speedup 1.0000x reference)
//
#include <hip/hip_runtime.h>

// GraphAttentionLayer: B=16, N=2048, F_IN=256, H=128 (fp32 in/out, adj int32)
//  k_wh  : MFMA bf16x3-split GEMM wh = X@W^T + bW (X,W staged in LDS);
//          fused src/dst dots (pre-scaled by log2e, ba folded into src);
//          writes wh in MFMA B-FRAGMENT order;
//          THEN compresses adj -> bitmask via coalesced ballot scan:
//          wave reads 256B contiguous/instr (lane=col), __ballot packs 64
//          cols, lane0 stores 8B. maskG[grow*64 + t] bit (c%32) = adj!=0.
//          (k_attn's own adj pattern was 32B slivers x 32k streams ->
//           ~45% DRAM efficiency, ~100us vs 43us floor. The stream moves
//           here where the access pattern is free.)
//  k_attn: barrier-free attention, ZERO HBM traffic in loop. Each wave owns
//          16 i-rows x all 128 h. Weights from bitmask (1 L1 dword/lane/chunk);
//          B-frags from whF (L2, XCD-swizzled grid). 8 MFMAs/chunk.
//          Softmax 1/l folded into epilogue. Literal-indexed slots (rule #20).

#define BDIM 16
#define NDIM 2048
#define FIN 256
#define HDIM 128
#define LOG2E 1.4426950408889634f

typedef short short8 __attribute__((ext_vector_type(8)));
typedef float floatx4 __attribute__((ext_vector_type(4)));

__device__ __forceinline__ unsigned short f2bf(float x) {
    unsigned int u = __float_as_uint(x);
    unsigned int r = (u + 0x7fffu + ((u >> 16) & 1u)) >> 16;  // RNE
    return (unsigned short)r;
}
__device__ __forceinline__ float bf2f(unsigned short s) {
    return __uint_as_float(((unsigned int)s) << 16);
}

// ---------------- Kernel 1: wh via MFMA (bf16 hi/lo split) + adj compress ----
// 64 rows x 128 h per block; 4 waves = 4 m-tiles of 16; K in panels of 64.
__global__ __launch_bounds__(256) void k_wh(const float* __restrict__ X,
                                            const int* __restrict__ adj,
                                            const float* __restrict__ W,
                                            const float* __restrict__ bW,
                                            const float* __restrict__ a,
                                            const float* __restrict__ ba_p,
                                            float* __restrict__ src,
                                            float* __restrict__ dst,
                                            unsigned short* __restrict__ whF,
                                            unsigned* __restrict__ maskG) {
    __shared__ short lds[27648];                    // 54 KB
    short (*ah)[72] = (short(*)[72])lds;
    short (*al)[72] = (short(*)[72])(lds + 4608);
    short (*bh)[72] = (short(*)[72])(lds + 9216);
    short (*bl)[72] = (short(*)[72])(lds + 18432);
    short (*tb)[72] = (short(*)[72])lds;            // epilogue alias [128][72]

    const int tid = threadIdx.x;
    const long row0 = (long)blockIdx.x * 64;
    const int w = tid >> 6, lane = tid & 63;
    const int lm = lane & 15, q = lane >> 4;
    const float ba0 = ba_p[0];

    float a1v[8], a2v[8], bwv[8];
    #pragma unroll
    for (int nt = 0; nt < 8; nt++) {
        a1v[nt] = a[nt * 16 + lm];
        a2v[nt] = a[HDIM + nt * 16 + lm];
        bwv[nt] = bW[nt * 16 + lm];
    }

    floatx4 acc[8];
    #pragma unroll
    for (int nt = 0; nt < 8; nt++) acc[nt] = (floatx4){0.f, 0.f, 0.f, 0.f};

    for (int k0 = 0; k0 < FIN; k0 += 64) {
        #pragma unroll
        for (int u = 0; u < 4; u++) {
            int idx = tid + u * 256;
            int r = idx >> 4, fc = (idx & 15) * 4;
            float4 v = *reinterpret_cast<const float4*>(X + (row0 + r) * FIN + k0 + fc);
            union { unsigned short s[4]; uint2 u2; } ph, pl;
            ph.s[0] = f2bf(v.x); pl.s[0] = f2bf(v.x - bf2f(ph.s[0]));
            ph.s[1] = f2bf(v.y); pl.s[1] = f2bf(v.y - bf2f(ph.s[1]));
            ph.s[2] = f2bf(v.z); pl.s[2] = f2bf(v.z - bf2f(ph.s[2]));
            ph.s[3] = f2bf(v.w); pl.s[3] = f2bf(v.w - bf2f(ph.s[3]));
            *reinterpret_cast<uint2*>(&ah[r][fc]) = ph.u2;
            *reinterpret_cast<uint2*>(&al[r][fc]) = pl.u2;
        }
        #pragma unroll
        for (int u = 0; u < 8; u++) {
            int idx = tid + u * 256;
            int hh = idx >> 4, fc = (idx & 15) * 4;
            float4 v = *reinterpret_cast<const float4*>(W + hh * FIN + k0 + fc);
            union { unsigned short s[4]; uint2 u2; } ph, pl;
            ph.s[0] = f2bf(v.x); pl.s[0] = f2bf(v.x - bf2f(ph.s[0]));
            ph.s[1] = f2bf(v.y); pl.s[1] = f2bf(v.y - bf2f(ph.s[1]));
            ph.s[2] = f2bf(v.z); pl.s[2] = f2bf(v.z - bf2f(ph.s[2]));
            ph.s[3] = f2bf(v.w); pl.s[3] = f2bf(v.w - bf2f(ph.s[3]));
            *reinterpret_cast<uint2*>(&bh[hh][fc]) = ph.u2;
            *reinterpret_cast<uint2*>(&bl[hh][fc]) = pl.u2;
        }
        __syncthreads();
        #pragma unroll
        for (int ks = 0; ks < 64; ks += 32) {
            short8 afh = *reinterpret_cast<const short8*>(&ah[w * 16 + lm][ks + q * 8]);
            short8 afl = *reinterpret_cast<const short8*>(&al[w * 16 + lm][ks + q * 8]);
            #pragma unroll
            for (int nt = 0; nt < 8; nt++) {
                short8 bfh = *reinterpret_cast<const short8*>(&bh[nt * 16 + lm][ks + q * 8]);
                short8 bfl = *reinterpret_cast<const short8*>(&bl[nt * 16 + lm][ks + q * 8]);
                acc[nt] = __builtin_amdgcn_mfma_f32_16x16x32_bf16(afh, bfh, acc[nt], 0, 0, 0);
                acc[nt] = __builtin_amdgcn_mfma_f32_16x16x32_bf16(afh, bfl, acc[nt], 0, 0, 0);
                acc[nt] = __builtin_amdgcn_mfma_f32_16x16x32_bf16(afl, bfh, acc[nt], 0, 0, 0);
            }
        }
        __syncthreads();
    }

    // epilogue: bias, src/dst dots, transpose via LDS -> B-fragment layout
    float s1[4] = {0.f, 0.f, 0.f, 0.f}, s2[4] = {0.f, 0.f, 0.f, 0.f};
    #pragma unroll
    for (int nt = 0; nt < 8; nt++) {
        #pragma unroll
        for (int r = 0; r < 4; r++) {
            float v = acc[nt][r] + bwv[nt];
            s1[r] += v * a1v[nt];
            s2[r] += v * a2v[nt];
            tb[nt * 16 + lm][w * 16 + q * 4 + r] = f2bf(v);   // tb[h][jrel]
        }
    }
    #pragma unroll
    for (int r = 0; r < 4; r++) {
        #pragma unroll
        for (int o = 1; o < 16; o <<= 1) {
            s1[r] += __shfl_xor(s1[r], o);
            s2[r] += __shfl_xor(s2[r], o);
        }
    }
    if (lm == 0) {
        #pragma unroll
        for (int r = 0; r < 4; r++) {
            long row = row0 + w * 16 + q * 4 + r;
            src[row] = (s1[r] + ba0) * LOG2E;   // fold bias-a + log2e (exp -> exp2)
            dst[row] = s2[r] * LOG2E;
        }
    }
    __syncthreads();
    // whF[b][jc][ht][l][e], frag = 512 shorts; block covers jc0..jc0+1
    const int b = (int)(row0 >> 11);
    const int jc0 = (int)((row0 & 2047) >> 5);
    const int f = tid >> 4;          // 0..15: jcrel = f>>3, ht = f&7
    const int sub = tid & 15;
    const int jcrel = f >> 3, ht = f & 7;
    const size_t fbase = (((size_t)b * 64 + jc0 + jcrel) * 8 + ht) * 512;
    #pragma unroll
    for (int i = 0; i < 4; i++) {
        int l = sub * 4 + i;
        uint4 v = *reinterpret_cast<const uint4*>(&tb[ht * 16 + (l & 15)][jcrel * 32 + (l >> 4) * 8]);
        *reinterpret_cast<uint4*>(whF + fbase + l * 8) = v;
    }

    // ---- adj -> bitmask compress (coalesced ballot scan) ----
    // wave w handles rows row0 + w*16 .. +15; per row 32 col-groups of 64.
    // Wave reads 256 B contiguous per instr (lane = col); __ballot packs
    // 64 cols; lane 0 stores 8 B. Nontemporal loads: don't evict whF.
    {
        #pragma unroll 1
        for (int ri = 0; ri < 16; ri++) {
            const size_t gr = (size_t)row0 + w * 16 + ri;
            const int* ar = adj + gr * NDIM + lane;
            unsigned* mo = maskG + gr * 64;
            #pragma unroll 8
            for (int ci = 0; ci < 32; ci++) {
                int v = __builtin_nontemporal_load(ar + ci * 64);
                unsigned long long bal = __ballot(v != 0);
                if (lane == 0) {
                    uint2 pk;
                    pk.x = (unsigned)bal;
                    pk.y = (unsigned)(bal >> 32);
                    *reinterpret_cast<uint2*>(mo + ci * 2) = pk;
                }
            }
        }
    }
}

// ---------------- Kernel 2: barrier-free streaming MFMA attention ----------------
// 512 blocks (XCD-swizzled); wave w owns i-rows i0+w*16..+15 (x all 128 h).
// No HBM traffic in the loop: weights from bitmask dword (L1), whF from L2.
// Literal slot indices only (rule #20: runtime-indexed regs -> scratch).
#define CH(T, PW)                                                              \
    do {                                                                       \
        if ((T) < NDIM / 32 - 1) {  /* prefetch chunk T+1 -> slot PW^1 */      \
            const float* dp = dstp + ((T) + 1) * 32;                           \
            d[(PW) ^ 1][0] = *reinterpret_cast<const floatx4*>(dp);            \
            d[(PW) ^ 1][1] = *reinterpret_cast<const floatx4*>(dp + 4);        \
            md[(PW) ^ 1] = mrow[(T) + 1];                                      \
            const unsigned short* wp = whFb + (size_t)((T) + 1) * 8 * 512;     \
            _Pragma("unroll")                                                  \
            for (int hj = 0; hj < 8; hj++)                                     \
                bfr[(PW) ^ 1][hj] =                                            \
                    *reinterpret_cast<const short8*>(wp + hj * 512);           \
        }                                                                      \
        const unsigned ms = md[(PW)] >> q8;  /* this lane's 8 mask bits */     \
        short8 af;                                                             \
        _Pragma("unroll")                                                      \
        for (int j = 0; j < 8; j++) {                                          \
            float x = si + d[(PW)][j >> 2][j & 3];                             \
            x = fmaxf(x, 0.01f * x);            /* leaky, scale-invariant */   \
            float e2 = __builtin_amdgcn_exp2f(x);                              \
            float wgt = (ms & (1u << j)) ? e2 : 0.f;                           \
            lpart += wgt;                                                      \
            af[j] = (short)f2bf(wgt);                                          \
        }                                                                      \
        _Pragma("unroll")                                                      \
        for (int hj = 0; hj < 8; hj++)                                         \
            acc[hj] = __builtin_amdgcn_mfma_f32_16x16x32_bf16(af, bfr[(PW)][hj], \
                                                              acc[hj], 0, 0, 0); \
    } while (0)

__global__ __launch_bounds__(256) void k_attn(const unsigned* __restrict__ maskG,
                                              const unsigned short* __restrict__ whF,
                                              const float* __restrict__ src,
                                              const float* __restrict__ dst,
                                              float* __restrict__ out) {
    __shared__ float lred[64];
    __shared__ float linv_s[64];

    const int tid = threadIdx.x;
    // XCD swizzle: 512 blocks, 8 XCDs -> XCD k gets a contiguous 64-block
    // chunk = batches 2k,2k+1. whF working set/XCD: 1 MB (L2-resident).
    const int bid = ((int)blockIdx.x & 7) * 64 + ((int)blockIdx.x >> 3);
    const int b = bid >> 5;                   // 32 i-tiles per batch
    const int i0 = (bid & 31) * 64;
    const int wave = tid >> 6, lane = tid & 63;
    const int lm = lane & 15, q = lane >> 4;
    const int q8 = q * 8;
    const int irow = i0 + wave * 16 + lm;

    const float si = src[b * NDIM + irow];    // includes ba and log2e scale
    const unsigned* mrow = maskG + (size_t)(b * NDIM + irow) * 64;
    const float* dstp = dst + b * NDIM + q8;
    const unsigned short* whFb = whF + (size_t)b * 64 * 8 * 512 + lane * 8;

    floatx4 acc[8];
    #pragma unroll
    for (int hj = 0; hj < 8; hj++) acc[hj] = (floatx4){0.f, 0.f, 0.f, 0.f};
    float lpart = 0.f;

    unsigned md[2];         // mask dword: double-buffer (L1-hot)
    floatx4 d[2][2];        // dst: double-buffer (L1/L2-hot)
    short8 bfr[2][8];       // whF: double-buffer (L2 after swizzle)
    md[0] = mrow[0];
    d[0][0] = *reinterpret_cast<const floatx4*>(dstp);
    d[0][1] = *reinterpret_cast<const floatx4*>(dstp + 4);
    #pragma unroll
    for (int hj = 0; hj < 8; hj++) bfr[0][hj] = *reinterpret_cast<const short8*>(whFb + hj * 512);

    for (int t = 0; t < NDIM / 32; t += 2) {
        CH(t + 0, 0);
        CH(t + 1, 1);
    }

    // denominator: combine the 4 q-slices of each row
    lpart += __shfl_xor(lpart, 16);
    lpart += __shfl_xor(lpart, 32);
    if (q == 0) lred[wave * 16 + lm] = lpart;
    __syncthreads();
    if (tid < 64) {
        float l = lred[tid];
        linv_s[tid] = l > 0.f ? 1.f / l : 0.f;
    }
    __syncthreads();

    // epilogue: scale 1/l, ELU, store (C/D: col=lm -> h, row=q*4+r -> i)
    #pragma unroll
    for (int r = 0; r < 4; r++) {
        int il = wave * 16 + q * 4 + r;
        float li = linv_s[il];
        size_t obase = ((size_t)(b * NDIM + i0 + il)) * HDIM + lm;
        #pragma unroll
        for (int hj = 0; hj < 8; hj++) {
            float x = acc[hj][r] * li;
            x = x > 0.f ? x : (__expf(x) - 1.f);
            out[obase + hj * 16] = x;
        }
    }
}

extern "C" void kernel_launch(void* const* d_in, const int* in_sizes, int n_in,
                              void* d_out, int out_size, void* d_ws, size_t ws_size,
                              hipStream_t stream) {
    const float* X  = (const float*)d_in[0];   // [16,2048,256]
    const int* adj  = (const int*)d_in[1];     // [16,2048,2048]
    const float* W  = (const float*)d_in[2];   // [128,256]
    const float* bW = (const float*)d_in[3];   // [128]
    const float* a  = (const float*)d_in[4];   // [1,256]
    const float* ba = (const float*)d_in[5];   // [1]
    float* out = (float*)d_out;                // [16,2048,128]

    float* srcv = (float*)d_ws;                                    // B*N
    float* dstv = srcv + BDIM * NDIM;                              // B*N
    unsigned short* whF = (unsigned short*)(dstv + BDIM * NDIM);   // 8.4 MB bf16 frag-order
    unsigned* maskG = (unsigned*)(whF + (size_t)BDIM * NDIM * HDIM); // 8.4 MB bitmask

    k_wh<<<BDIM * NDIM / 64, 256, 0, stream>>>(X, adj, W, bW, a, ba, srcv, dstv, whF, maskG);
    k_attn<<<BDIM * (NDIM / 64), 256, 0, stream>>>(maskG, whF, srcv, dstv, out);
}

// Round 5
// 430.414 us; speedup vs baseline: 1.4064x; 1.4064x over previous
//
#include <hip/hip_runtime.h>

// GraphAttentionLayer: B=16, N=2048, F_IN=256, H=128 (fp32 in/out, adj int32)
//  k_pack: adj -> bitmask, BATCHED ballot scan. v[32] loaded before any
//          ballot (R4 lesson: load->ballot->store per iter serializes at
//          vmcnt(0) x 512 = ~233us; batching makes it HBM-bound ~45us).
//  k_wh  : MFMA bf16x3-split GEMM wh = X@W^T + bW; fused src/dst dots
//          (log2e + ba folded); writes wh in MFMA B-FRAGMENT order.
//  k_attn: attention. Wave owns 16 i-rows x all 128 h. whF chunk staged in
//          LDS once per block (was: 4 waves x 8KB from L2 each = 1.07GB L2
//          = the 44us limiter; now 268MB). Weights from bitmask (L1 dword).
//          Reg-staged issue-early/write-late, 1 barrier/chunk. Literal slot
//          indices only (rule #20).

#define BDIM 16
#define NDIM 2048
#define FIN 256
#define HDIM 128
#define LOG2E 1.4426950408889634f

typedef short short8 __attribute__((ext_vector_type(8)));
typedef float floatx4 __attribute__((ext_vector_type(4)));

__device__ __forceinline__ unsigned short f2bf(float x) {
    unsigned int u = __float_as_uint(x);
    unsigned int r = (u + 0x7fffu + ((u >> 16) & 1u)) >> 16;  // RNE
    return (unsigned short)r;
}
__device__ __forceinline__ float bf2f(unsigned short s) {
    return __uint_as_float(((unsigned int)s) << 16);
}

// ---------------- Kernel 0: adj -> bitmask (batched ballot) ----------------
// 2048 blocks x 4 waves; wave packs 4 rows. Per row: 32 coalesced 256B loads
// ALL issued first (v[32], program order), then 32 ballots, then lane0 stores
// 8 uint4. maskG[row*64 + t] bit j = (adj[row][t*32+j] != 0).
__global__ __launch_bounds__(256) void k_pack(const int* __restrict__ adj,
                                              unsigned* __restrict__ maskG) {
    const int tid = threadIdx.x;
    const int wave = tid >> 6, lane = tid & 63;
    const size_t row0 = (size_t)blockIdx.x * 16 + wave * 4;

    #pragma unroll 1
    for (int r = 0; r < 4; r++) {
        const int* ar = adj + (row0 + r) * NDIM + lane;
        int v[32];
        #pragma unroll
        for (int u = 0; u < 32; u++)
            v[u] = __builtin_nontemporal_load(ar + u * 64);
        unsigned pk[16];
        #pragma unroll
        for (int u = 0; u < 16; u++) {
            unsigned long long b = __ballot(v[u] != 0);
            pk[u] = 0;  // placeholder to keep indices literal; overwritten below
            (void)b;
        }
        // redo cleanly: 32 ballots -> 64 dwords held as 16 uint4-halves
        unsigned lo[32], hi[32];
        #pragma unroll
        for (int u = 0; u < 32; u++) {
            unsigned long long b = __ballot(v[u] != 0);
            lo[u] = (unsigned)b;
            hi[u] = (unsigned)(b >> 32);
        }
        if (lane == 0) {
            unsigned* mo = maskG + (row0 + r) * 64;
            #pragma unroll
            for (int u = 0; u < 16; u++) {
                uint4 o;
                o.x = lo[2 * u];
                o.y = hi[2 * u];
                o.z = lo[2 * u + 1];
                o.w = hi[2 * u + 1];
                *reinterpret_cast<uint4*>(mo + u * 4) = o;
            }
        }
        (void)pk;
    }
}

// ---------------- Kernel 1: wh via MFMA (bf16 hi/lo split) ----------------
// 64 rows x 128 h per block; 4 waves = 4 m-tiles of 16; K in panels of 64.
__global__ __launch_bounds__(256) void k_wh(const float* __restrict__ X,
                                            const float* __restrict__ W,
                                            const float* __restrict__ bW,
                                            const float* __restrict__ a,
                                            const float* __restrict__ ba_p,
                                            float* __restrict__ src,
                                            float* __restrict__ dst,
                                            unsigned short* __restrict__ whF) {
    __shared__ short lds[27648];                    // 54 KB
    short (*ah)[72] = (short(*)[72])lds;
    short (*al)[72] = (short(*)[72])(lds + 4608);
    short (*bh)[72] = (short(*)[72])(lds + 9216);
    short (*bl)[72] = (short(*)[72])(lds + 18432);
    short (*tb)[72] = (short(*)[72])lds;            // epilogue alias [128][72]

    const int tid = threadIdx.x;
    const long row0 = (long)blockIdx.x * 64;
    const int w = tid >> 6, lane = tid & 63;
    const int lm = lane & 15, q = lane >> 4;
    const float ba0 = ba_p[0];

    float a1v[8], a2v[8], bwv[8];
    #pragma unroll
    for (int nt = 0; nt < 8; nt++) {
        a1v[nt] = a[nt * 16 + lm];
        a2v[nt] = a[HDIM + nt * 16 + lm];
        bwv[nt] = bW[nt * 16 + lm];
    }

    floatx4 acc[8];
    #pragma unroll
    for (int nt = 0; nt < 8; nt++) acc[nt] = (floatx4){0.f, 0.f, 0.f, 0.f};

    for (int k0 = 0; k0 < FIN; k0 += 64) {
        #pragma unroll
        for (int u = 0; u < 4; u++) {
            int idx = tid + u * 256;
            int r = idx >> 4, fc = (idx & 15) * 4;
            float4 v = *reinterpret_cast<const float4*>(X + (row0 + r) * FIN + k0 + fc);
            union { unsigned short s[4]; uint2 u2; } ph, pl;
            ph.s[0] = f2bf(v.x); pl.s[0] = f2bf(v.x - bf2f(ph.s[0]));
            ph.s[1] = f2bf(v.y); pl.s[1] = f2bf(v.y - bf2f(ph.s[1]));
            ph.s[2] = f2bf(v.z); pl.s[2] = f2bf(v.z - bf2f(ph.s[2]));
            ph.s[3] = f2bf(v.w); pl.s[3] = f2bf(v.w - bf2f(ph.s[3]));
            *reinterpret_cast<uint2*>(&ah[r][fc]) = ph.u2;
            *reinterpret_cast<uint2*>(&al[r][fc]) = pl.u2;
        }
        #pragma unroll
        for (int u = 0; u < 8; u++) {
            int idx = tid + u * 256;
            int hh = idx >> 4, fc = (idx & 15) * 4;
            float4 v = *reinterpret_cast<const float4*>(W + hh * FIN + k0 + fc);
            union { unsigned short s[4]; uint2 u2; } ph, pl;
            ph.s[0] = f2bf(v.x); pl.s[0] = f2bf(v.x - bf2f(ph.s[0]));
            ph.s[1] = f2bf(v.y); pl.s[1] = f2bf(v.y - bf2f(ph.s[1]));
            ph.s[2] = f2bf(v.z); pl.s[2] = f2bf(v.z - bf2f(ph.s[2]));
            ph.s[3] = f2bf(v.w); pl.s[3] = f2bf(v.w - bf2f(ph.s[3]));
            *reinterpret_cast<uint2*>(&bh[hh][fc]) = ph.u2;
            *reinterpret_cast<uint2*>(&bl[hh][fc]) = pl.u2;
        }
        __syncthreads();
        #pragma unroll
        for (int ks = 0; ks < 64; ks += 32) {
            short8 afh = *reinterpret_cast<const short8*>(&ah[w * 16 + lm][ks + q * 8]);
            short8 afl = *reinterpret_cast<const short8*>(&al[w * 16 + lm][ks + q * 8]);
            #pragma unroll
            for (int nt = 0; nt < 8; nt++) {
                short8 bfh = *reinterpret_cast<const short8*>(&bh[nt * 16 + lm][ks + q * 8]);
                short8 bfl = *reinterpret_cast<const short8*>(&bl[nt * 16 + lm][ks + q * 8]);
                acc[nt] = __builtin_amdgcn_mfma_f32_16x16x32_bf16(afh, bfh, acc[nt], 0, 0, 0);
                acc[nt] = __builtin_amdgcn_mfma_f32_16x16x32_bf16(afh, bfl, acc[nt], 0, 0, 0);
                acc[nt] = __builtin_amdgcn_mfma_f32_16x16x32_bf16(afl, bfh, acc[nt], 0, 0, 0);
            }
        }
        __syncthreads();
    }

    // epilogue: bias, src/dst dots, transpose via LDS -> B-fragment layout
    float s1[4] = {0.f, 0.f, 0.f, 0.f}, s2[4] = {0.f, 0.f, 0.f, 0.f};
    #pragma unroll
    for (int nt = 0; nt < 8; nt++) {
        #pragma unroll
        for (int r = 0; r < 4; r++) {
            float v = acc[nt][r] + bwv[nt];
            s1[r] += v * a1v[nt];
            s2[r] += v * a2v[nt];
            tb[nt * 16 + lm][w * 16 + q * 4 + r] = f2bf(v);   // tb[h][jrel]
        }
    }
    #pragma unroll
    for (int r = 0; r < 4; r++) {
        #pragma unroll
        for (int o = 1; o < 16; o <<= 1) {
            s1[r] += __shfl_xor(s1[r], o);
            s2[r] += __shfl_xor(s2[r], o);
        }
    }
    if (lm == 0) {
        #pragma unroll
        for (int r = 0; r < 4; r++) {
            long row = row0 + w * 16 + q * 4 + r;
            src[row] = (s1[r] + ba0) * LOG2E;   // fold bias-a + log2e (exp -> exp2)
            dst[row] = s2[r] * LOG2E;
        }
    }
    __syncthreads();
    // whF[b][jc][ht][l][e], frag = 512 shorts; block covers jc0..jc0+1
    const int b = (int)(row0 >> 11);
    const int jc0 = (int)((row0 & 2047) >> 5);
    const int f = tid >> 4;          // 0..15: jcrel = f>>3, ht = f&7
    const int sub = tid & 15;
    const int jcrel = f >> 3, ht = f & 7;
    const size_t fbase = (((size_t)b * 64 + jc0 + jcrel) * 8 + ht) * 512;
    #pragma unroll
    for (int i = 0; i < 4; i++) {
        int l = sub * 4 + i;
        uint4 v = *reinterpret_cast<const uint4*>(&tb[ht * 16 + (l & 15)][jcrel * 32 + (l >> 4) * 8]);
        *reinterpret_cast<uint4*>(whF + fbase + l * 8) = v;
    }
}

// ---------------- Kernel 2: LDS-staged streaming MFMA attention ------------
// 512 blocks (XCD-swizzled); wave w owns i-rows i0+w*16..+15 (x all 128 h).
// Per chunk: block stages 8KB whF chunk in LDS dbuf (4 waves x 1KB each,
// issue-early/write-late); weights from bitmask dword; 8 MFMAs; 1 barrier.
#define CH(T, PW)                                                              \
    do {                                                                       \
        short8 s0, s1;                                                         \
        if ((T) < 63) { /* issue next-chunk loads early (hide under MFMA) */   \
            const unsigned short* gp = gsrc + (size_t)((T) + 1) * 4096;        \
            s0 = *reinterpret_cast<const short8*>(gp);                         \
            s1 = *reinterpret_cast<const short8*>(gp + 512);                   \
            const float* dp = dstp + ((T) + 1) * 32;                           \
            d[(PW) ^ 1][0] = *reinterpret_cast<const floatx4*>(dp);            \
            d[(PW) ^ 1][1] = *reinterpret_cast<const floatx4*>(dp + 4);        \
            md[(PW) ^ 1] = mrow[(T) + 1];                                      \
        }                                                                      \
        const unsigned ms = md[(PW)] >> q8;  /* this lane's 8 mask bits */     \
        short8 af;                                                             \
        _Pragma("unroll")                                                      \
        for (int j = 0; j < 8; j++) {                                          \
            float x = si + d[(PW)][j >> 2][j & 3];                             \
            x = fmaxf(x, 0.01f * x);            /* leaky, scale-invariant */   \
            float e2 = __builtin_amdgcn_exp2f(x);                              \
            float wgt = (ms & (1u << j)) ? e2 : 0.f;                           \
            lpart += wgt;                                                      \
            af[j] = (short)f2bf(wgt);                                          \
        }                                                                      \
        _Pragma("unroll")                                                      \
        for (int hj = 0; hj < 8; hj++) {                                       \
            short8 fb = *reinterpret_cast<const short8*>(                      \
                &whS[(PW)][hj * 512 + lane * 8]);                              \
            acc[hj] = __builtin_amdgcn_mfma_f32_16x16x32_bf16(af, fb,          \
                                                              acc[hj], 0, 0, 0); \
        }                                                                      \
        if ((T) < 63) { /* write-late: staged data -> other LDS buffer */      \
            *reinterpret_cast<short8*>(ldst + ((PW) ^ 1) * 4096) = s0;         \
            *reinterpret_cast<short8*>(ldst + ((PW) ^ 1) * 4096 + 512) = s1;   \
        }                                                                      \
        __syncthreads();                                                       \
    } while (0)

__global__ __launch_bounds__(256) void k_attn(const unsigned* __restrict__ maskG,
                                              const unsigned short* __restrict__ whF,
                                              const float* __restrict__ src,
                                              const float* __restrict__ dst,
                                              float* __restrict__ out) {
    __shared__ short whS[2][4096];   // 16 KB: staged whF chunk (8 frags) x2
    __shared__ float lred[64];
    __shared__ float linv_s[64];

    const int tid = threadIdx.x;
    // XCD swizzle: 512 blocks, 8 XCDs -> XCD k gets a contiguous 64-block
    // chunk = batches 2k,2k+1. whF working set/XCD: 1 MB (L2-resident).
    const int bid = ((int)blockIdx.x & 7) * 64 + ((int)blockIdx.x >> 3);
    const int b = bid >> 5;                   // 32 i-tiles per batch
    const int i0 = (bid & 31) * 64;
    const int wave = tid >> 6, lane = tid & 63;
    const int lm = lane & 15, q = lane >> 4;
    const int q8 = q * 8;
    const int irow = i0 + wave * 16 + lm;

    const float si = src[b * NDIM + irow];    // includes ba and log2e scale
    const unsigned* mrow = maskG + (size_t)(b * NDIM + irow) * 64;
    const float* dstp = dst + b * NDIM + q8;
    // staging: chunk = 4096 shorts; wave w copies shorts [w*1024, w*1024+1024)
    const unsigned short* gsrc =
        whF + (size_t)b * 64 * 8 * 512 + wave * 1024 + lane * 8;
    short* ldst = &whS[0][0] + wave * 1024 + lane * 8;

    floatx4 acc[8];
    #pragma unroll
    for (int hj = 0; hj < 8; hj++) acc[hj] = (floatx4){0.f, 0.f, 0.f, 0.f};
    float lpart = 0.f;

    unsigned md[2];         // mask dword: double-buffer (L1/L2-hot)
    floatx4 d[2][2];        // dst: double-buffer (L1/L2-hot)

    // prologue: stage chunk 0 -> buf 0; prefetch md/d slot 0
    {
        short8 s0 = *reinterpret_cast<const short8*>(gsrc);
        short8 s1 = *reinterpret_cast<const short8*>(gsrc + 512);
        *reinterpret_cast<short8*>(ldst) = s0;
        *reinterpret_cast<short8*>(ldst + 512) = s1;
    }
    md[0] = mrow[0];
    d[0][0] = *reinterpret_cast<const floatx4*>(dstp);
    d[0][1] = *reinterpret_cast<const floatx4*>(dstp + 4);
    __syncthreads();

    for (int t = 0; t < NDIM / 32; t += 2) {
        CH(t + 0, 0);
        CH(t + 1, 1);
    }

    // denominator: combine the 4 q-slices of each row
    lpart += __shfl_xor(lpart, 16);
    lpart += __shfl_xor(lpart, 32);
    if (q == 0) lred[wave * 16 + lm] = lpart;
    __syncthreads();
    if (tid < 64) {
        float l = lred[tid];
        linv_s[tid] = l > 0.f ? 1.f / l : 0.f;
    }
    __syncthreads();

    // epilogue: scale 1/l, ELU, store (C/D: col=lm -> h, row=q*4+r -> i)
    #pragma unroll
    for (int r = 0; r < 4; r++) {
        int il = wave * 16 + q * 4 + r;
        float li = linv_s[il];
        size_t obase = ((size_t)(b * NDIM + i0 + il)) * HDIM + lm;
        #pragma unroll
        for (int hj = 0; hj < 8; hj++) {
            float x = acc[hj][r] * li;
            x = x > 0.f ? x : (__expf(x) - 1.f);
            out[obase + hj * 16] = x;
        }
    }
}

extern "C" void kernel_launch(void* const* d_in, const int* in_sizes, int n_in,
                              void* d_out, int out_size, void* d_ws, size_t ws_size,
                              hipStream_t stream) {
    const float* X  = (const float*)d_in[0];   // [16,2048,256]
    const int* adj  = (const int*)d_in[1];     // [16,2048,2048]
    const float* W  = (const float*)d_in[2];   // [128,256]
    const float* bW = (const float*)d_in[3];   // [128]
    const float* a  = (const float*)d_in[4];   // [1,256]
    const float* ba = (const float*)d_in[5];   // [1]
    float* out = (float*)d_out;                // [16,2048,128]

    float* srcv = (float*)d_ws;                                    // B*N
    float* dstv = srcv + BDIM * NDIM;                              // B*N
    unsigned short* whF = (unsigned short*)(dstv + BDIM * NDIM);   // 8.4 MB bf16 frag-order
    unsigned* maskG = (unsigned*)(whF + (size_t)BDIM * NDIM * HDIM); // 8.4 MB bitmask

    k_pack<<<2048, 256, 0, stream>>>(adj, maskG);
    k_wh<<<BDIM * NDIM / 64, 256, 0, stream>>>(X, W, bW, a, ba, srcv, dstv, whF);
    k_attn<<<BDIM * (NDIM / 64), 256, 0, stream>>>(maskG, whF, srcv, dstv, out);
}

// Round 6
// 417.533 us; speedup vs baseline: 1.4498x; 1.0309x over previous
//
#include <hip/hip_runtime.h>

// GraphAttentionLayer: B=16, N=2048, F_IN=256, H=128 (fp32 in/out, adj int32)
//  k_wh  : MFMA bf16x3-split GEMM wh = X@W^T + bW; fused src/dst dots
//          (log2e + ba folded); writes wh in MFMA B-FRAGMENT order.
//  k_attn: FUSED pack+attention. Prologue: block packs its OWN 64 adj rows
//          -> LDS bitmask (coalesced 256B batched-ballot reads; adj read
//          exactly once device-wide, 268MB, overlaps MFMA loop across
//          phase-skewed blocks; kills the separate k_pack launch + the
//          16.8MB maskG HBM round-trip). Loop: R5 structure -- whF chunk
//          staged in LDS dbuf (L2 traffic 1GB->268MB), weights from LDS
//          mask dword, 8 MFMAs/chunk, 1 barrier/chunk, literal slot
//          indices only (rule #20). Softmax 1/l folded into epilogue.

#define BDIM 16
#define NDIM 2048
#define FIN 256
#define HDIM 128
#define LOG2E 1.4426950408889634f

typedef short short8 __attribute__((ext_vector_type(8)));
typedef float floatx4 __attribute__((ext_vector_type(4)));

__device__ __forceinline__ unsigned short f2bf(float x) {
    unsigned int u = __float_as_uint(x);
    unsigned int r = (u + 0x7fffu + ((u >> 16) & 1u)) >> 16;  // RNE
    return (unsigned short)r;
}
__device__ __forceinline__ float bf2f(unsigned short s) {
    return __uint_as_float(((unsigned int)s) << 16);
}

// ---------------- Kernel 1: wh via MFMA (bf16 hi/lo split) ----------------
// 64 rows x 128 h per block; 4 waves = 4 m-tiles of 16; K in panels of 64.
__global__ __launch_bounds__(256) void k_wh(const float* __restrict__ X,
                                            const float* __restrict__ W,
                                            const float* __restrict__ bW,
                                            const float* __restrict__ a,
                                            const float* __restrict__ ba_p,
                                            float* __restrict__ src,
                                            float* __restrict__ dst,
                                            unsigned short* __restrict__ whF) {
    __shared__ short lds[27648];                    // 54 KB
    short (*ah)[72] = (short(*)[72])lds;
    short (*al)[72] = (short(*)[72])(lds + 4608);
    short (*bh)[72] = (short(*)[72])(lds + 9216);
    short (*bl)[72] = (short(*)[72])(lds + 18432);
    short (*tb)[72] = (short(*)[72])lds;            // epilogue alias [128][72]

    const int tid = threadIdx.x;
    const long row0 = (long)blockIdx.x * 64;
    const int w = tid >> 6, lane = tid & 63;
    const int lm = lane & 15, q = lane >> 4;
    const float ba0 = ba_p[0];

    float a1v[8], a2v[8], bwv[8];
    #pragma unroll
    for (int nt = 0; nt < 8; nt++) {
        a1v[nt] = a[nt * 16 + lm];
        a2v[nt] = a[HDIM + nt * 16 + lm];
        bwv[nt] = bW[nt * 16 + lm];
    }

    floatx4 acc[8];
    #pragma unroll
    for (int nt = 0; nt < 8; nt++) acc[nt] = (floatx4){0.f, 0.f, 0.f, 0.f};

    for (int k0 = 0; k0 < FIN; k0 += 64) {
        #pragma unroll
        for (int u = 0; u < 4; u++) {
            int idx = tid + u * 256;
            int r = idx >> 4, fc = (idx & 15) * 4;
            float4 v = *reinterpret_cast<const float4*>(X + (row0 + r) * FIN + k0 + fc);
            union { unsigned short s[4]; uint2 u2; } ph, pl;
            ph.s[0] = f2bf(v.x); pl.s[0] = f2bf(v.x - bf2f(ph.s[0]));
            ph.s[1] = f2bf(v.y); pl.s[1] = f2bf(v.y - bf2f(ph.s[1]));
            ph.s[2] = f2bf(v.z); pl.s[2] = f2bf(v.z - bf2f(ph.s[2]));
            ph.s[3] = f2bf(v.w); pl.s[3] = f2bf(v.w - bf2f(ph.s[3]));
            *reinterpret_cast<uint2*>(&ah[r][fc]) = ph.u2;
            *reinterpret_cast<uint2*>(&al[r][fc]) = pl.u2;
        }
        #pragma unroll
        for (int u = 0; u < 8; u++) {
            int idx = tid + u * 256;
            int hh = idx >> 4, fc = (idx & 15) * 4;
            float4 v = *reinterpret_cast<const float4*>(W + hh * FIN + k0 + fc);
            union { unsigned short s[4]; uint2 u2; } ph, pl;
            ph.s[0] = f2bf(v.x); pl.s[0] = f2bf(v.x - bf2f(ph.s[0]));
            ph.s[1] = f2bf(v.y); pl.s[1] = f2bf(v.y - bf2f(ph.s[1]));
            ph.s[2] = f2bf(v.z); pl.s[2] = f2bf(v.z - bf2f(ph.s[2]));
            ph.s[3] = f2bf(v.w); pl.s[3] = f2bf(v.w - bf2f(ph.s[3]));
            *reinterpret_cast<uint2*>(&bh[hh][fc]) = ph.u2;
            *reinterpret_cast<uint2*>(&bl[hh][fc]) = pl.u2;
        }
        __syncthreads();
        #pragma unroll
        for (int ks = 0; ks < 64; ks += 32) {
            short8 afh = *reinterpret_cast<const short8*>(&ah[w * 16 + lm][ks + q * 8]);
            short8 afl = *reinterpret_cast<const short8*>(&al[w * 16 + lm][ks + q * 8]);
            #pragma unroll
            for (int nt = 0; nt < 8; nt++) {
                short8 bfh = *reinterpret_cast<const short8*>(&bh[nt * 16 + lm][ks + q * 8]);
                short8 bfl = *reinterpret_cast<const short8*>(&bl[nt * 16 + lm][ks + q * 8]);
                acc[nt] = __builtin_amdgcn_mfma_f32_16x16x32_bf16(afh, bfh, acc[nt], 0, 0, 0);
                acc[nt] = __builtin_amdgcn_mfma_f32_16x16x32_bf16(afh, bfl, acc[nt], 0, 0, 0);
                acc[nt] = __builtin_amdgcn_mfma_f32_16x16x32_bf16(afl, bfh, acc[nt], 0, 0, 0);
            }
        }
        __syncthreads();
    }

    // epilogue: bias, src/dst dots, transpose via LDS -> B-fragment layout
    float s1[4] = {0.f, 0.f, 0.f, 0.f}, s2[4] = {0.f, 0.f, 0.f, 0.f};
    #pragma unroll
    for (int nt = 0; nt < 8; nt++) {
        #pragma unroll
        for (int r = 0; r < 4; r++) {
            float v = acc[nt][r] + bwv[nt];
            s1[r] += v * a1v[nt];
            s2[r] += v * a2v[nt];
            tb[nt * 16 + lm][w * 16 + q * 4 + r] = f2bf(v);   // tb[h][jrel]
        }
    }
    #pragma unroll
    for (int r = 0; r < 4; r++) {
        #pragma unroll
        for (int o = 1; o < 16; o <<= 1) {
            s1[r] += __shfl_xor(s1[r], o);
            s2[r] += __shfl_xor(s2[r], o);
        }
    }
    if (lm == 0) {
        #pragma unroll
        for (int r = 0; r < 4; r++) {
            long row = row0 + w * 16 + q * 4 + r;
            src[row] = (s1[r] + ba0) * LOG2E;   // fold bias-a + log2e (exp -> exp2)
            dst[row] = s2[r] * LOG2E;
        }
    }
    __syncthreads();
    // whF[b][jc][ht][l][e], frag = 512 shorts; block covers jc0..jc0+1
    const int b = (int)(row0 >> 11);
    const int jc0 = (int)((row0 & 2047) >> 5);
    const int f = tid >> 4;          // 0..15: jcrel = f>>3, ht = f&7
    const int sub = tid & 15;
    const int jcrel = f >> 3, ht = f & 7;
    const size_t fbase = (((size_t)b * 64 + jc0 + jcrel) * 8 + ht) * 512;
    #pragma unroll
    for (int i = 0; i < 4; i++) {
        int l = sub * 4 + i;
        uint4 v = *reinterpret_cast<const uint4*>(&tb[ht * 16 + (l & 15)][jcrel * 32 + (l >> 4) * 8]);
        *reinterpret_cast<uint4*>(whF + fbase + l * 8) = v;
    }
}

// ---------------- Kernel 2: fused pack + LDS-staged MFMA attention --------
// 512 blocks (XCD-swizzled); wave w owns i-rows i0+w*16..+15 (x all 128 h).
// Prologue packs the block's own 64 adj rows into maskS (LDS). Loop: whF
// chunk staged in LDS dbuf; weights from maskS dword; 8 MFMAs; 1 barrier.
#define CH(T, PW)                                                              \
    do {                                                                       \
        short8 s0, s1;                                                         \
        if ((T) < 63) { /* issue next-chunk loads early (hide under MFMA) */   \
            const unsigned short* gp = gsrc + (size_t)((T) + 1) * 4096;        \
            s0 = *reinterpret_cast<const short8*>(gp);                         \
            s1 = *reinterpret_cast<const short8*>(gp + 512);                   \
            const float* dp = dstp + ((T) + 1) * 32;                           \
            d[(PW) ^ 1][0] = *reinterpret_cast<const floatx4*>(dp);            \
            d[(PW) ^ 1][1] = *reinterpret_cast<const floatx4*>(dp + 4);        \
            md[(PW) ^ 1] = maskS[wrow][(T) + 1];                               \
        }                                                                      \
        const unsigned ms = md[(PW)] >> q8;  /* this lane's 8 mask bits */     \
        short8 af;                                                             \
        _Pragma("unroll")                                                      \
        for (int j = 0; j < 8; j++) {                                          \
            float x = si + d[(PW)][j >> 2][j & 3];                             \
            x = fmaxf(x, 0.01f * x);            /* leaky, scale-invariant */   \
            float e2 = __builtin_amdgcn_exp2f(x);                              \
            float wgt = (ms & (1u << j)) ? e2 : 0.f;                           \
            lpart += wgt;                                                      \
            af[j] = (short)f2bf(wgt);                                          \
        }                                                                      \
        _Pragma("unroll")                                                      \
        for (int hj = 0; hj < 8; hj++) {                                       \
            short8 fb = *reinterpret_cast<const short8*>(                      \
                &whS[(PW)][hj * 512 + lane * 8]);                              \
            acc[hj] = __builtin_amdgcn_mfma_f32_16x16x32_bf16(af, fb,          \
                                                              acc[hj], 0, 0, 0); \
        }                                                                      \
        if ((T) < 63) { /* write-late: staged data -> other LDS buffer */      \
            *reinterpret_cast<short8*>(ldst + ((PW) ^ 1) * 4096) = s0;         \
            *reinterpret_cast<short8*>(ldst + ((PW) ^ 1) * 4096 + 512) = s1;   \
        }                                                                      \
        __syncthreads();                                                       \
    } while (0)

__global__ __launch_bounds__(256) void k_attn(const int* __restrict__ adj,
                                              const unsigned short* __restrict__ whF,
                                              const float* __restrict__ src,
                                              const float* __restrict__ dst,
                                              float* __restrict__ out) {
    __shared__ short whS[2][4096];     // 16 KB: staged whF chunk (8 frags) x2
    __shared__ unsigned maskS[64][66]; // 16.9 KB: adj bitmask, stride 66
                                       // (8B-aligned uint2 writes; loop reads
                                       //  bank 2*lm+t -> conflict-free)
    __shared__ float lred[64];
    __shared__ float linv_s[64];

    const int tid = threadIdx.x;
    // XCD swizzle: 512 blocks, 8 XCDs -> XCD k gets a contiguous 64-block
    // chunk = batches 2k,2k+1. whF working set/XCD: 1 MB (L2-resident).
    const int bid = ((int)blockIdx.x & 7) * 64 + ((int)blockIdx.x >> 3);
    const int b = bid >> 5;                   // 32 i-tiles per batch
    const int i0 = (bid & 31) * 64;
    const int wave = tid >> 6, lane = tid & 63;
    const int lm = lane & 15, q = lane >> 4;
    const int q8 = q * 8;
    const int wrow = wave * 16 + lm;          // local i-row this lane owns
    const int irow = i0 + wrow;

    // ---- pack prologue: wave w packs local rows w*16..w*16+15 ----
    // Per row: 32 coalesced 256B loads batched BEFORE ballots (R4 lesson:
    // interleaved load->ballot serializes at vmcnt(0)). adj read exactly
    // once device-wide. Nontemporal: don't evict whF from L2.
    {
        #pragma unroll 1
        for (int ri = 0; ri < 16; ri++) {
            const int lr = wave * 16 + ri;
            const int* ar = adj + ((size_t)b * NDIM + i0 + lr) * NDIM + lane;
            int v[32];
            #pragma unroll
            for (int u = 0; u < 32; u++)
                v[u] = __builtin_nontemporal_load(ar + u * 64);
            #pragma unroll
            for (int u = 0; u < 32; u++) {
                unsigned long long bal = __ballot(v[u] != 0);
                if (lane == 0) {
                    uint2 pk;
                    pk.x = (unsigned)bal;
                    pk.y = (unsigned)(bal >> 32);
                    *reinterpret_cast<uint2*>(&maskS[lr][2 * u]) = pk;
                }
            }
        }
    }

    const float si = src[b * NDIM + irow];    // includes ba and log2e scale
    const float* dstp = dst + b * NDIM + q8;
    // staging: chunk = 4096 shorts; wave w copies shorts [w*1024, w*1024+1024)
    const unsigned short* gsrc =
        whF + (size_t)b * 64 * 8 * 512 + wave * 1024 + lane * 8;
    short* ldst = &whS[0][0] + wave * 1024 + lane * 8;

    floatx4 acc[8];
    #pragma unroll
    for (int hj = 0; hj < 8; hj++) acc[hj] = (floatx4){0.f, 0.f, 0.f, 0.f};
    float lpart = 0.f;

    unsigned md[2];         // mask dword: double-buffer (LDS-sourced)
    floatx4 d[2][2];        // dst: double-buffer (L1/L2-hot)

    // prologue: stage chunk 0 -> buf 0; then barrier covers maskS + whS[0]
    {
        short8 s0 = *reinterpret_cast<const short8*>(gsrc);
        short8 s1 = *reinterpret_cast<const short8*>(gsrc + 512);
        *reinterpret_cast<short8*>(ldst) = s0;
        *reinterpret_cast<short8*>(ldst + 512) = s1;
    }
    d[0][0] = *reinterpret_cast<const floatx4*>(dstp);
    d[0][1] = *reinterpret_cast<const floatx4*>(dstp + 4);
    __syncthreads();
    md[0] = maskS[wrow][0];

    for (int t = 0; t < NDIM / 32; t += 2) {
        CH(t + 0, 0);
        CH(t + 1, 1);
    }

    // denominator: combine the 4 q-slices of each row
    lpart += __shfl_xor(lpart, 16);
    lpart += __shfl_xor(lpart, 32);
    if (q == 0) lred[wave * 16 + lm] = lpart;
    __syncthreads();
    if (tid < 64) {
        float l = lred[tid];
        linv_s[tid] = l > 0.f ? 1.f / l : 0.f;
    }
    __syncthreads();

    // epilogue: scale 1/l, ELU, store (C/D: col=lm -> h, row=q*4+r -> i)
    #pragma unroll
    for (int r = 0; r < 4; r++) {
        int il = wave * 16 + q * 4 + r;
        float li = linv_s[il];
        size_t obase = ((size_t)(b * NDIM + i0 + il)) * HDIM + lm;
        #pragma unroll
        for (int hj = 0; hj < 8; hj++) {
            float x = acc[hj][r] * li;
            x = x > 0.f ? x : (__expf(x) - 1.f);
            out[obase + hj * 16] = x;
        }
    }
}

extern "C" void kernel_launch(void* const* d_in, const int* in_sizes, int n_in,
                              void* d_out, int out_size, void* d_ws, size_t ws_size,
                              hipStream_t stream) {
    const float* X  = (const float*)d_in[0];   // [16,2048,256]
    const int* adj  = (const int*)d_in[1];     // [16,2048,2048]
    const float* W  = (const float*)d_in[2];   // [128,256]
    const float* bW = (const float*)d_in[3];   // [128]
    const float* a  = (const float*)d_in[4];   // [1,256]
    const float* ba = (const float*)d_in[5];   // [1]
    float* out = (float*)d_out;                // [16,2048,128]

    float* srcv = (float*)d_ws;                                    // B*N
    float* dstv = srcv + BDIM * NDIM;                              // B*N
    unsigned short* whF = (unsigned short*)(dstv + BDIM * NDIM);   // 8.4 MB bf16 frag-order

    k_wh<<<BDIM * NDIM / 64, 256, 0, stream>>>(X, W, bW, a, ba, srcv, dstv, whF);
    k_attn<<<BDIM * (NDIM / 64), 256, 0, stream>>>(adj, whF, srcv, dstv, out);
}